// Round 9
// baseline (209.647 us; speedup 1.0000x reference)
//
#include <hip/hip_runtime.h>
#include <stdint.h>

// BinarizeLinear inference: out = sign(X) @ sign(W) + bias
// Round 9: i8 MFMA 256x256 8-phase GEMM with FRAGMENT-BLOCKED operand layout
// (pre-permuted at pack time): 1KB blocks [G][kt][g][p][lane][16B] so staging
// gloads are linear, LDS dest linear, and every ds_read_b128 is a contiguous
// 1KB wave read -> zero bank conflicts. Exact integer math.

#define N_ROWS 8192
#define K_DIM  4096
#define O_DIM  4096
#define KW     64

typedef int int4v  __attribute__((ext_vector_type(4)));
typedef int int16v __attribute__((ext_vector_type(16)));

// ====================== pack / convert helpers ==============================
__global__ __launch_bounds__(256) void pack_w_kernel(
        const float* __restrict__ W, uint64_t* __restrict__ Wb) {
    int oc = blockIdx.x & 15;
    int w  = blockIdx.x >> 4;
    int o  = oc * 256 + threadIdx.x;
    const float* wp = W + (size_t)(w * 64) * O_DIM + o;
    uint64_t word = 0;
    #pragma unroll 8
    for (int p = 0; p < 64; ++p) {
        float v = wp[(size_t)p * O_DIM];
        word |= (uint64_t)(v > 0.0f) << p;
    }
    Wb[(size_t)o * KW + w] = word;
}

// X -> i8 (+1/-1) in fragment-blocked layout. Thread handles 16 consecutive k
// of one row = exactly one 16B fragment piece (G,kt,g,p,lh,l31).
__global__ __launch_bounds__(256) void convert_x_kernel(
        const float* __restrict__ X, int8_t* __restrict__ XBlk) {
    size_t i = ((size_t)blockIdx.x * 256 + threadIdx.x) * 16;
    const float4* xp = (const float4*)(X + i);
    uint32_t ow[4];
    #pragma unroll
    for (int q = 0; q < 4; ++q) {
        float4 v = xp[q];
        uint32_t b0 = v.x > 0.0f ? 0x01u : 0xFFu;
        uint32_t b1 = v.y > 0.0f ? 0x01u : 0xFFu;
        uint32_t b2 = v.z > 0.0f ? 0x01u : 0xFFu;
        uint32_t b3 = v.w > 0.0f ? 0x01u : 0xFFu;
        ow[q] = b0 | (b1 << 8) | (b2 << 16) | (b3 << 24);
    }
    int4v o; o.x = ow[0]; o.y = ow[1]; o.z = ow[2]; o.w = ow[3];

    int n  = (int)(i >> 12);          // row
    int k0 = (int)(i & 4095);
    int G = n >> 8, r = n & 255, g = r >> 5, l31 = r & 31;
    int kt = k0 >> 7, kb = k0 & 127, p = kb >> 5, lh = (kb >> 4) & 1;
    size_t off = (((size_t)(G * 32 + kt) * 32 + g * 4 + p) * 64
                  + lh * 32 + l31) * 16;
    *(int4v*)(XBlk + off) = o;
}

// bit-packed Wb (u32 view) -> i8 (+1/-1) fragment-blocked layout. One u32
// (32 k-bits of one out-row) = one p-block = two 16B pieces (lh=0,1).
__global__ __launch_bounds__(256) void expand_wt_kernel(
        const uint32_t* __restrict__ Wb32, int8_t* __restrict__ WBlk) {
    size_t t = (size_t)blockIdx.x * 256 + threadIdx.x;   // o*128 + j32
    uint32_t w = Wb32[t];
    uint32_t ow[8];
    #pragma unroll
    for (int q = 0; q < 8; ++q) {
        uint32_t v = 0;
        #pragma unroll
        for (int b = 0; b < 4; ++b)
            v |= (((w >> (4 * q + b)) & 1u) ? 0x01u : 0xFFu) << (8 * b);
        ow[q] = v;
    }
    int4v o0; o0.x = ow[0]; o0.y = ow[1]; o0.z = ow[2]; o0.w = ow[3];
    int4v o1; o1.x = ow[4]; o1.y = ow[5]; o1.z = ow[6]; o1.w = ow[7];

    int o   = (int)(t >> 7);
    int j32 = (int)(t & 127);
    int G = o >> 8, r = o & 255, g = r >> 5, l31 = r & 31;
    int kt = j32 >> 2, p = j32 & 3;
    size_t blk = ((size_t)(G * 32 + kt) * 32 + g * 4 + p) * 1024;
    *(int4v*)(WBlk + blk + l31 * 16)        = o0;   // lh=0: k [0,16)
    *(int4v*)(WBlk + blk + 512 + l31 * 16)  = o1;   // lh=1: k [16,32)
}

// ====================== 256x256 8-phase i8 GEMM =============================
// 512 blocks (32M x 16N), 512 thr / 8 waves, per-wave 128x64 (4x2 of 32x32).
// BK=128. LDS 128 KiB: [buf][A 32KB | B 32KB]. All gloads & ds_reads are
// contiguous 1KB wave ops in the blocked layout — no swizzle needed.
__global__ __launch_bounds__(512, 2) void i8_gemm256_kernel(
        const int8_t* __restrict__ XBlk, const int8_t* __restrict__ WBlk,
        const float* __restrict__ bias, float* __restrict__ out) {
    __shared__ int8_t lds[2 * 65536];    // 128 KiB

    const int tid  = threadIdx.x;
    // XCD-aware swizzle: 512 blocks, 512%8==0 -> bijective
    const int swzb = (blockIdx.x & 7) * 64 + (blockIdx.x >> 3);
    const int brow = (swzb >> 4) * 256;
    const int bcol = (swzb & 15) * 256;

    const int lane = tid & 63;
    const int wid  = tid >> 6;
    const int wrow = (wid >> 2) * 128;   // 2 M-groups
    const int wcol = (wid & 3) * 64;     // 4 N-groups
    const int l31  = lane & 31;
    const int lh   = lane >> 5;

    const int abase = wrow * 128 + lane * 16;           // A block g0=wrow>>5
    const int bbase = 32768 + wcol * 128 + lane * 16;   // B block g0=wcol>>5

    const size_t ldst0 = (size_t)tid * 16;
    const int8_t* Asrc = XBlk + ((size_t)brow << 12) + ldst0;  // (brow>>8)<<20
    const int8_t* Bsrc = WBlk + ((size_t)bcol << 12) + ldst0;

#define GLOADS(srcbase, ldsoff, kt)                                           \
    {                                                                         \
        _Pragma("unroll")                                                     \
        for (int i = 0; i < 4; ++i) {                                         \
            __builtin_amdgcn_global_load_lds(                                 \
                (const __attribute__((address_space(1))) void*)               \
                    ((srcbase) + (size_t)(kt) * 32768 + i * 8192),            \
                (__attribute__((address_space(3))) void*)                     \
                    (lds + (ldsoff) + ldst0 + i * 8192), 16, 0, 0);           \
        }                                                                     \
    }

    int16v c00 = 0, c01 = 0, c10 = 0, c11 = 0, c20 = 0, c21 = 0, c30 = 0, c31 = 0;

    // prologue: stage tile 0 into buf 0
    GLOADS(Asrc, 0, 0);
    GLOADS(Bsrc, 32768, 0);
    asm volatile("s_waitcnt vmcnt(0)" ::: "memory");
    __builtin_amdgcn_s_barrier();

#define PHASE(p, STAGE_BLK)                                                   \
    {                                                                         \
        const int8_t* Ap = lds + curoff + abase + ((p) << 10);                \
        const int8_t* Bp = lds + curoff + bbase + ((p) << 10);                \
        int4v a0 = *(const int4v*)(Ap);                                       \
        int4v a1 = *(const int4v*)(Ap + 4096);                                \
        int4v a2 = *(const int4v*)(Ap + 8192);                                \
        int4v a3 = *(const int4v*)(Ap + 12288);                               \
        int4v b0 = *(const int4v*)(Bp);                                       \
        int4v b1 = *(const int4v*)(Bp + 4096);                                \
        STAGE_BLK;                                                            \
        __builtin_amdgcn_s_barrier();                                         \
        __builtin_amdgcn_s_setprio(1);                                        \
        c00 = __builtin_amdgcn_mfma_i32_32x32x32_i8(a0, b0, c00, 0, 0, 0);    \
        c01 = __builtin_amdgcn_mfma_i32_32x32x32_i8(a0, b1, c01, 0, 0, 0);    \
        c10 = __builtin_amdgcn_mfma_i32_32x32x32_i8(a1, b0, c10, 0, 0, 0);    \
        c11 = __builtin_amdgcn_mfma_i32_32x32x32_i8(a1, b1, c11, 0, 0, 0);    \
        c20 = __builtin_amdgcn_mfma_i32_32x32x32_i8(a2, b0, c20, 0, 0, 0);    \
        c21 = __builtin_amdgcn_mfma_i32_32x32x32_i8(a2, b1, c21, 0, 0, 0);    \
        c30 = __builtin_amdgcn_mfma_i32_32x32x32_i8(a3, b0, c30, 0, 0, 0);    \
        c31 = __builtin_amdgcn_mfma_i32_32x32x32_i8(a3, b1, c31, 0, 0, 0);    \
        __builtin_amdgcn_s_setprio(0);                                        \
    }

    for (int t = 0; t < K_DIM / 128; ++t) {
        const int curoff = (t & 1) << 16;
        const int nxtoff = curoff ^ 65536;
        const bool pf = (t < K_DIM / 128 - 1);

        PHASE(0, { if (pf) GLOADS(Asrc, nxtoff, t + 1); });
        __builtin_amdgcn_s_barrier();
        PHASE(1, { if (pf) GLOADS(Bsrc, nxtoff + 32768, t + 1); });
        __builtin_amdgcn_s_barrier();
        PHASE(2, {});
        __builtin_amdgcn_s_barrier();
        PHASE(3, {});
        asm volatile("s_waitcnt vmcnt(0)" ::: "memory");
        __builtin_amdgcn_s_barrier();
    }
#undef PHASE
#undef GLOADS

    // epilogue: C/D map col=lane&31, row=(r&3)+8*(r>>2)+4*(lane>>5)
    float bv0 = bias[bcol + wcol + l31];
    float bv1 = bias[bcol + wcol + 32 + l31];
    const size_t obase = (size_t)(brow + wrow) * O_DIM + bcol + wcol;

#define CWRITE(cm, m, n, bv)                                                  \
    {                                                                         \
        _Pragma("unroll")                                                     \
        for (int r = 0; r < 16; ++r) {                                        \
            int rl = (r & 3) + 8 * (r >> 2) + 4 * lh;                         \
            out[obase + (size_t)((m) * 32 + rl) * O_DIM + (n) * 32 + l31] =   \
                (float)cm[r] + (bv);                                          \
        }                                                                     \
    }

    CWRITE(c00, 0, 0, bv0); CWRITE(c01, 0, 1, bv1);
    CWRITE(c10, 1, 0, bv0); CWRITE(c11, 1, 1, bv1);
    CWRITE(c20, 2, 0, bv0); CWRITE(c21, 2, 1, bv1);
    CWRITE(c30, 3, 0, bv0); CWRITE(c31, 3, 1, bv1);
#undef CWRITE
}

// ====================== popcount fallback (round-5, proven) =================
__global__ __launch_bounds__(256) void pack_x_kernel(
        const float* __restrict__ X, uint64_t* __restrict__ Xb) {
    int wave = (int)((blockIdx.x * blockDim.x + threadIdx.x) >> 6);
    int lane = threadIdx.x & 63;
    if (wave >= N_ROWS) return;
    const float* xr = X + (size_t)wave * K_DIM;
    uint64_t* xbr = Xb + (size_t)wave * KW;
    #pragma unroll 4
    for (int w = 0; w < KW; ++w) {
        float v = xr[w * 64 + lane];
        unsigned long long m = __ballot(v > 0.0f);
        if (lane == 0) xbr[w] = (uint64_t)m;
    }
}

__global__ __launch_bounds__(256) void xnor_gemm_kernel(
        const uint8_t* __restrict__ Xb, const uint8_t* __restrict__ Wb,
        const float* __restrict__ bias, float* __restrict__ out) {
    __shared__ uint4 lds4[2048];
    const int tid    = threadIdx.x;
    const int brow   = (blockIdx.x >> 5) * 128;
    const int bcol   = (blockIdx.x & 31) * 128;
    const int tx     = tid & 15;
    const int ty     = tid >> 4;
    const int widx   = tid >> 6;
    const int xbase0 = ty * 64 + (ty & 7);
    const int wbase0 = 1024 + tx * 64 + (tx & 7);
    uint32_t acc[8][8] = {};
    for (int kc = 0; kc < 4; ++kc) {
        __syncthreads();
        #pragma unroll
        for (int i = 0; i < 4; ++i) {
            int idx  = tid + 256 * i;
            int row  = idx >> 3;
            int srcc = (idx & 7) ^ ((idx >> 6) & 7);
            size_t goff = ((size_t)row << 9) + (kc << 7) + (srcc << 4);
            __builtin_amdgcn_global_load_lds(
                (const __attribute__((address_space(1))) void*)
                    (Xb + ((size_t)brow << 9) + goff),
                (__attribute__((address_space(3))) void*)
                    (lds4 + i * 256 + widx * 64), 16, 0, 0);
            __builtin_amdgcn_global_load_lds(
                (const __attribute__((address_space(1))) void*)
                    (Wb + ((size_t)bcol << 9) + goff),
                (__attribute__((address_space(3))) void*)
                    (lds4 + 1024 + i * 256 + widx * 64), 16, 0, 0);
        }
        asm volatile("s_waitcnt vmcnt(0)" ::: "memory");
        __syncthreads();
        for (int kq = 0; kq < 8; ++kq) {
            const uint4* xp = &lds4[xbase0 ^ kq];
            const uint4* wp = &lds4[wbase0 ^ kq];
            uint4 xq[8];
            #pragma unroll
            for (int r = 0; r < 8; ++r) xq[r] = xp[8 * r];
            #pragma unroll
            for (int c = 0; c < 8; ++c) {
                uint4 wv = wp[8 * c];
                #pragma unroll
                for (int r = 0; r < 8; ++r) {
                    uint32_t a = acc[r][c];
                    a = __builtin_popcount(xq[r].x ^ wv.x) + a;
                    a = __builtin_popcount(xq[r].y ^ wv.y) + a;
                    a = __builtin_popcount(xq[r].z ^ wv.z) + a;
                    a = __builtin_popcount(xq[r].w ^ wv.w) + a;
                    acc[r][c] = a;
                }
            }
        }
    }
    float bv[8];
    #pragma unroll
    for (int c = 0; c < 8; ++c) bv[c] = bias[bcol + tx * 8 + c];
    #pragma unroll
    for (int r = 0; r < 8; ++r) {
        float vals[8];
        #pragma unroll
        for (int c = 0; c < 8; ++c)
            vals[c] = (float)(K_DIM - 2 * (int)acc[r][c]) + bv[c];
        float4* op = (float4*)(out + (size_t)(brow + ty * 8 + r) * O_DIM
                               + bcol + tx * 8);
        op[0] = make_float4(vals[0], vals[1], vals[2], vals[3]);
        op[1] = make_float4(vals[4], vals[5], vals[6], vals[7]);
    }
}

// ====================== launcher ============================================
extern "C" void kernel_launch(void* const* d_in, const int* in_sizes, int n_in,
                              void* d_out, int out_size, void* d_ws, size_t ws_size,
                              hipStream_t stream) {
    const float* X    = (const float*)d_in[0];
    const float* W    = (const float*)d_in[1];
    const float* bias = (const float*)d_in[2];
    float* out        = (float*)d_out;

    const size_t XB_BYTES = (size_t)N_ROWS * K_DIM;   // 32 MiB blocked X
    const size_t WB_BYTES = (size_t)O_DIM * K_DIM;    // 16 MiB blocked W
    const size_t PK_BYTES = (size_t)O_DIM * KW * 8;   //  2 MiB bit-packed W

    if (ws_size >= XB_BYTES + WB_BYTES + PK_BYTES) {
        int8_t*   XBlk = (int8_t*)d_ws;
        int8_t*   WBlk = (int8_t*)d_ws + XB_BYTES;
        uint64_t* Wb   = (uint64_t*)((uint8_t*)d_ws + XB_BYTES + WB_BYTES);

        convert_x_kernel<<<(N_ROWS * K_DIM) / (256 * 16), 256, 0, stream>>>(X, XBlk);
        pack_w_kernel<<<16 * 64, 256, 0, stream>>>(W, Wb);
        expand_wt_kernel<<<(O_DIM * 128) / 256, 256, 0, stream>>>(
            (const uint32_t*)Wb, WBlk);
        i8_gemm256_kernel<<<(N_ROWS / 256) * (O_DIM / 256), 512, 0, stream>>>(
            XBlk, WBlk, bias, out);
    } else {
        uint64_t* Xb = (uint64_t*)d_ws;
        uint64_t* Wb = (uint64_t*)((uint8_t*)d_ws + (size_t)N_ROWS * KW * 8);
        pack_x_kernel<<<N_ROWS / 4, 256, 0, stream>>>(X, Xb);
        pack_w_kernel<<<16 * 64, 256, 0, stream>>>(W, Wb);
        xnor_gemm_kernel<<<(N_ROWS / 128) * (O_DIM / 128), 256, 0, stream>>>(
            (const uint8_t*)Xb, (const uint8_t*)Wb, bias, out);
    }
}

// Round 10
// 187.103 us; speedup vs baseline: 1.1205x; 1.1205x over previous
//
#include <hip/hip_runtime.h>
#include <stdint.h>

// BinarizeLinear inference: out = sign(X) @ sign(W) + bias
// Round 10: (a) GEMM de-barriered — only the semantically-required tile-edge
// vmcnt+barrier remains (intra-tile phases touch disjoint LDS); (b) pack
// kernels rewritten wave-aligned: each wave owns one 1KB fragment block,
// lane l writes blk+l*16 (contiguous); W converted directly from f32
// (replaces pack_w + expand_wt). Exact integer math throughout.

#define N_ROWS 8192
#define K_DIM  4096
#define O_DIM  4096
#define KW     64

typedef int int4v  __attribute__((ext_vector_type(4)));
typedef int int16v __attribute__((ext_vector_type(16)));

// ====================== X -> fragment-blocked i8 ============================
// Piece u = [G][kt][g][p] (1KB). Lane l: row n=G*256+g*32+(l&31),
// k = kt*128+p*32+(l>>5)*16 .. +16. Wave writes contiguous 1KB.
__global__ __launch_bounds__(256) void convert_x_kernel(
        const float* __restrict__ X, int8_t* __restrict__ XBlk) {
    int u    = blockIdx.x * 4 + (threadIdx.x >> 6);   // wave id, [0, 32768)
    int lane = threadIdx.x & 63;
    int p  = u & 3, g = (u >> 2) & 7, kt = (u >> 5) & 31, G = u >> 10;
    int n    = G * 256 + g * 32 + (lane & 31);
    int kcol = kt * 128 + p * 32 + (lane >> 5) * 16;
    const float4* src = (const float4*)(X + (size_t)n * K_DIM + kcol);
    uint32_t ow[4];
    #pragma unroll
    for (int q = 0; q < 4; ++q) {
        float4 v = src[q];
        uint32_t b0 = v.x > 0.0f ? 0x01u : 0xFFu;
        uint32_t b1 = v.y > 0.0f ? 0x01u : 0xFFu;
        uint32_t b2 = v.z > 0.0f ? 0x01u : 0xFFu;
        uint32_t b3 = v.w > 0.0f ? 0x01u : 0xFFu;
        ow[q] = b0 | (b1 << 8) | (b2 << 16) | (b3 << 24);
    }
    int4v o; o.x = ow[0]; o.y = ow[1]; o.z = ow[2]; o.w = ow[3];
    *(int4v*)(XBlk + (size_t)u * 1024 + lane * 16) = o;
}

// ====================== W (f32 [in][out]) -> blocked i8 WT ==================
// Same piece scheme over o. Lane l: o=G*256+g*32+(l&31),
// k = kt*128+p*32+(l>>5)*16 + j, j=0..15. Reads: half-wave reads
// W[k][o..o+32) = 128B coalesced segments. Wave writes contiguous 1KB.
__global__ __launch_bounds__(256) void convert_w_kernel(
        const float* __restrict__ W, int8_t* __restrict__ WBlk) {
    int u    = blockIdx.x * 4 + (threadIdx.x >> 6);   // wave id, [0, 16384)
    int lane = threadIdx.x & 63;
    int p  = u & 3, g = (u >> 2) & 7, kt = (u >> 5) & 31, G = u >> 10;
    int o     = G * 256 + g * 32 + (lane & 31);
    int kbase = kt * 128 + p * 32 + (lane >> 5) * 16;
    const float* src = W + (size_t)kbase * O_DIM + o;
    uint32_t ow[4];
    #pragma unroll
    for (int q = 0; q < 4; ++q) {
        uint32_t v = 0;
        #pragma unroll
        for (int b = 0; b < 4; ++b) {
            float f = src[(size_t)(q * 4 + b) * O_DIM];
            v |= (f > 0.0f ? 0x01u : 0xFFu) << (8 * b);
        }
        ow[q] = v;
    }
    int4v ov; ov.x = ow[0]; ov.y = ow[1]; ov.z = ow[2]; ov.w = ow[3];
    *(int4v*)(WBlk + (size_t)u * 1024 + lane * 16) = ov;
}

// ====================== 256x256 i8 GEMM, 1 barrier/tile =====================
// 512 blocks (32M x 16N), 512 thr / 8 waves, per-wave 128x64 (4x2 of 32x32).
// BK=128. LDS 128 KiB [buf][A 32KB | B 32KB]. Intra-tile phases read disjoint
// 1KB-block regions -> no intra-tile barriers; tile edge: vmcnt(0)+barrier.
__global__ __launch_bounds__(512, 2) void i8_gemm256_kernel(
        const int8_t* __restrict__ XBlk, const int8_t* __restrict__ WBlk,
        const float* __restrict__ bias, float* __restrict__ out) {
    __shared__ int8_t lds[2 * 65536];    // 128 KiB

    const int tid  = threadIdx.x;
    const int swzb = (blockIdx.x & 7) * 64 + (blockIdx.x >> 3);  // XCD swizzle
    const int brow = (swzb >> 4) * 256;
    const int bcol = (swzb & 15) * 256;

    const int lane = tid & 63;
    const int wid  = tid >> 6;
    const int wrow = (wid >> 2) * 128;   // 2 M-groups
    const int wcol = (wid & 3) * 64;     // 4 N-groups
    const int l31  = lane & 31;
    const int lh   = lane >> 5;

    const int abase = wrow * 128 + lane * 16;
    const int bbase = 32768 + wcol * 128 + lane * 16;

    const size_t ldst0 = (size_t)tid * 16;
    const int8_t* Asrc = XBlk + ((size_t)brow << 12) + ldst0;
    const int8_t* Bsrc = WBlk + ((size_t)bcol << 12) + ldst0;

#define GLOADS(srcbase, ldsoff, kt)                                           \
    {                                                                         \
        _Pragma("unroll")                                                     \
        for (int i = 0; i < 4; ++i) {                                         \
            __builtin_amdgcn_global_load_lds(                                 \
                (const __attribute__((address_space(1))) void*)               \
                    ((srcbase) + (size_t)(kt) * 32768 + i * 8192),            \
                (__attribute__((address_space(3))) void*)                     \
                    (lds + (ldsoff) + ldst0 + i * 8192), 16, 0, 0);           \
        }                                                                     \
    }

    int16v c00 = 0, c01 = 0, c10 = 0, c11 = 0, c20 = 0, c21 = 0, c30 = 0, c31 = 0;

    // prologue: stage tile 0 into buf 0
    GLOADS(Asrc, 0, 0);
    GLOADS(Bsrc, 32768, 0);
    asm volatile("s_waitcnt vmcnt(0)" ::: "memory");
    __builtin_amdgcn_s_barrier();

#define PHASE(p, STAGE_BLK)                                                   \
    {                                                                         \
        const int8_t* Ap = lds + curoff + abase + ((p) << 10);                \
        const int8_t* Bp = lds + curoff + bbase + ((p) << 10);                \
        int4v a0 = *(const int4v*)(Ap);                                       \
        int4v a1 = *(const int4v*)(Ap + 4096);                                \
        int4v a2 = *(const int4v*)(Ap + 8192);                                \
        int4v a3 = *(const int4v*)(Ap + 12288);                               \
        int4v b0 = *(const int4v*)(Bp);                                       \
        int4v b1 = *(const int4v*)(Bp + 4096);                                \
        STAGE_BLK;                                                            \
        __builtin_amdgcn_s_setprio(1);                                        \
        c00 = __builtin_amdgcn_mfma_i32_32x32x32_i8(a0, b0, c00, 0, 0, 0);    \
        c01 = __builtin_amdgcn_mfma_i32_32x32x32_i8(a0, b1, c01, 0, 0, 0);    \
        c10 = __builtin_amdgcn_mfma_i32_32x32x32_i8(a1, b0, c10, 0, 0, 0);    \
        c11 = __builtin_amdgcn_mfma_i32_32x32x32_i8(a1, b1, c11, 0, 0, 0);    \
        c20 = __builtin_amdgcn_mfma_i32_32x32x32_i8(a2, b0, c20, 0, 0, 0);    \
        c21 = __builtin_amdgcn_mfma_i32_32x32x32_i8(a2, b1, c21, 0, 0, 0);    \
        c30 = __builtin_amdgcn_mfma_i32_32x32x32_i8(a3, b0, c30, 0, 0, 0);    \
        c31 = __builtin_amdgcn_mfma_i32_32x32x32_i8(a3, b1, c31, 0, 0, 0);    \
        __builtin_amdgcn_s_setprio(0);                                        \
    }

    for (int t = 0; t < K_DIM / 128; ++t) {
        const int curoff = (t & 1) << 16;
        const int nxtoff = curoff ^ 65536;
        const bool pf = (t < K_DIM / 128 - 1);

        // no intra-tile barriers: phases read disjoint LDS; waves free-run
        PHASE(0, { if (pf) GLOADS(Asrc, nxtoff, t + 1); });
        PHASE(1, { if (pf) GLOADS(Bsrc, nxtoff + 32768, t + 1); });
        PHASE(2, {});
        PHASE(3, {});
        asm volatile("s_waitcnt vmcnt(0)" ::: "memory");  // own staging landed
        __builtin_amdgcn_s_barrier();                     // all reads+stages done
    }
#undef PHASE
#undef GLOADS

    // epilogue: C/D map col=lane&31, row=(r&3)+8*(r>>2)+4*(lane>>5)
    float bv0 = bias[bcol + wcol + l31];
    float bv1 = bias[bcol + wcol + 32 + l31];
    const size_t obase = (size_t)(brow + wrow) * O_DIM + bcol + wcol;

#define CWRITE(cm, m, n, bv)                                                  \
    {                                                                         \
        _Pragma("unroll")                                                     \
        for (int r = 0; r < 16; ++r) {                                        \
            int rl = (r & 3) + 8 * (r >> 2) + 4 * lh;                         \
            out[obase + (size_t)((m) * 32 + rl) * O_DIM + (n) * 32 + l31] =   \
                (float)cm[r] + (bv);                                          \
        }                                                                     \
    }

    CWRITE(c00, 0, 0, bv0); CWRITE(c01, 0, 1, bv1);
    CWRITE(c10, 1, 0, bv0); CWRITE(c11, 1, 1, bv1);
    CWRITE(c20, 2, 0, bv0); CWRITE(c21, 2, 1, bv1);
    CWRITE(c30, 3, 0, bv0); CWRITE(c31, 3, 1, bv1);
#undef CWRITE
}

// ====================== popcount fallback (round-5, proven) =================
__global__ __launch_bounds__(256) void pack_x_kernel(
        const float* __restrict__ X, uint64_t* __restrict__ Xb) {
    int wave = (int)((blockIdx.x * blockDim.x + threadIdx.x) >> 6);
    int lane = threadIdx.x & 63;
    if (wave >= N_ROWS) return;
    const float* xr = X + (size_t)wave * K_DIM;
    uint64_t* xbr = Xb + (size_t)wave * KW;
    #pragma unroll 4
    for (int w = 0; w < KW; ++w) {
        float v = xr[w * 64 + lane];
        unsigned long long m = __ballot(v > 0.0f);
        if (lane == 0) xbr[w] = (uint64_t)m;
    }
}

__global__ __launch_bounds__(256) void pack_w_kernel(
        const float* __restrict__ W, uint64_t* __restrict__ Wb) {
    int oc = blockIdx.x & 15;
    int w  = blockIdx.x >> 4;
    int o  = oc * 256 + threadIdx.x;
    const float* wp = W + (size_t)(w * 64) * O_DIM + o;
    uint64_t word = 0;
    #pragma unroll 8
    for (int p = 0; p < 64; ++p) {
        float v = wp[(size_t)p * O_DIM];
        word |= (uint64_t)(v > 0.0f) << p;
    }
    Wb[(size_t)o * KW + w] = word;
}

__global__ __launch_bounds__(256) void xnor_gemm_kernel(
        const uint8_t* __restrict__ Xb, const uint8_t* __restrict__ Wb,
        const float* __restrict__ bias, float* __restrict__ out) {
    __shared__ uint4 lds4[2048];
    const int tid    = threadIdx.x;
    const int brow   = (blockIdx.x >> 5) * 128;
    const int bcol   = (blockIdx.x & 31) * 128;
    const int tx     = tid & 15;
    const int ty     = tid >> 4;
    const int widx   = tid >> 6;
    const int xbase0 = ty * 64 + (ty & 7);
    const int wbase0 = 1024 + tx * 64 + (tx & 7);
    uint32_t acc[8][8] = {};
    for (int kc = 0; kc < 4; ++kc) {
        __syncthreads();
        #pragma unroll
        for (int i = 0; i < 4; ++i) {
            int idx  = tid + 256 * i;
            int row  = idx >> 3;
            int srcc = (idx & 7) ^ ((idx >> 6) & 7);
            size_t goff = ((size_t)row << 9) + (kc << 7) + (srcc << 4);
            __builtin_amdgcn_global_load_lds(
                (const __attribute__((address_space(1))) void*)
                    (Xb + ((size_t)brow << 9) + goff),
                (__attribute__((address_space(3))) void*)
                    (lds4 + i * 256 + widx * 64), 16, 0, 0);
            __builtin_amdgcn_global_load_lds(
                (const __attribute__((address_space(1))) void*)
                    (Wb + ((size_t)bcol << 9) + goff),
                (__attribute__((address_space(3))) void*)
                    (lds4 + 1024 + i * 256 + widx * 64), 16, 0, 0);
        }
        asm volatile("s_waitcnt vmcnt(0)" ::: "memory");
        __syncthreads();
        for (int kq = 0; kq < 8; ++kq) {
            const uint4* xp = &lds4[xbase0 ^ kq];
            const uint4* wp = &lds4[wbase0 ^ kq];
            uint4 xq[8];
            #pragma unroll
            for (int r = 0; r < 8; ++r) xq[r] = xp[8 * r];
            #pragma unroll
            for (int c = 0; c < 8; ++c) {
                uint4 wv = wp[8 * c];
                #pragma unroll
                for (int r = 0; r < 8; ++r) {
                    uint32_t a = acc[r][c];
                    a = __builtin_popcount(xq[r].x ^ wv.x) + a;
                    a = __builtin_popcount(xq[r].y ^ wv.y) + a;
                    a = __builtin_popcount(xq[r].z ^ wv.z) + a;
                    a = __builtin_popcount(xq[r].w ^ wv.w) + a;
                    acc[r][c] = a;
                }
            }
        }
    }
    float bv[8];
    #pragma unroll
    for (int c = 0; c < 8; ++c) bv[c] = bias[bcol + tx * 8 + c];
    #pragma unroll
    for (int r = 0; r < 8; ++r) {
        float vals[8];
        #pragma unroll
        for (int c = 0; c < 8; ++c)
            vals[c] = (float)(K_DIM - 2 * (int)acc[r][c]) + bv[c];
        float4* op = (float4*)(out + (size_t)(brow + ty * 8 + r) * O_DIM
                               + bcol + tx * 8);
        op[0] = make_float4(vals[0], vals[1], vals[2], vals[3]);
        op[1] = make_float4(vals[4], vals[5], vals[6], vals[7]);
    }
}

// ====================== launcher ============================================
extern "C" void kernel_launch(void* const* d_in, const int* in_sizes, int n_in,
                              void* d_out, int out_size, void* d_ws, size_t ws_size,
                              hipStream_t stream) {
    const float* X    = (const float*)d_in[0];
    const float* W    = (const float*)d_in[1];
    const float* bias = (const float*)d_in[2];
    float* out        = (float*)d_out;

    const size_t XB_BYTES = (size_t)N_ROWS * K_DIM;   // 32 MiB blocked X
    const size_t WB_BYTES = (size_t)O_DIM * K_DIM;    // 16 MiB blocked W

    if (ws_size >= XB_BYTES + WB_BYTES) {
        int8_t* XBlk = (int8_t*)d_ws;
        int8_t* WBlk = (int8_t*)d_ws + XB_BYTES;

        convert_x_kernel<<<(N_ROWS * K_DIM / 16) / 256, 256, 0, stream>>>(X, XBlk);
        convert_w_kernel<<<(O_DIM * K_DIM / 16) / 256, 256, 0, stream>>>(W, WBlk);
        i8_gemm256_kernel<<<(N_ROWS / 256) * (O_DIM / 256), 512, 0, stream>>>(
            XBlk, WBlk, bias, out);
    } else {
        uint64_t* Xb = (uint64_t*)d_ws;
        uint64_t* Wb = (uint64_t*)((uint8_t*)d_ws + (size_t)N_ROWS * KW * 8);
        pack_x_kernel<<<N_ROWS / 4, 256, 0, stream>>>(X, Xb);
        pack_w_kernel<<<16 * 64, 256, 0, stream>>>(W, Wb);
        xnor_gemm_kernel<<<(N_ROWS / 128) * (O_DIM / 128), 256, 0, stream>>>(
            (const uint8_t*)Xb, (const uint8_t*)Wb, bias, out);
    }
}

// Round 12
// 184.774 us; speedup vs baseline: 1.1346x; 1.0126x over previous
//
#include <hip/hip_runtime.h>
#include <stdint.h>

// BinarizeLinear inference: out = sign(X) @ sign(W) + bias
// Round 11: register double-buffered fragments in the i8 GEMM — phase p+1's
// 6 ds_read_b128 issue BEFORE phase p's MFMA cluster (two named fragment
// sets, static regs), so the lgkm wait is counted, not a full drain, and the
// LDS pipe runs under the MFMA pipe within each wave. Packing unchanged
// (wave-aligned fragment-blocked layout, direct f32->i8). Exact integer math.

#define N_ROWS 8192
#define K_DIM  4096
#define O_DIM  4096
#define KW     64

typedef int int4v  __attribute__((ext_vector_type(4)));
typedef int int16v __attribute__((ext_vector_type(16)));

// ====================== X -> fragment-blocked i8 ============================
__global__ __launch_bounds__(256) void convert_x_kernel(
        const float* __restrict__ X, int8_t* __restrict__ XBlk) {
    int u    = blockIdx.x * 4 + (threadIdx.x >> 6);   // wave id, [0, 32768)
    int lane = threadIdx.x & 63;
    int p  = u & 3, g = (u >> 2) & 7, kt = (u >> 5) & 31, G = u >> 10;
    int n    = G * 256 + g * 32 + (lane & 31);
    int kcol = kt * 128 + p * 32 + (lane >> 5) * 16;
    const float4* src = (const float4*)(X + (size_t)n * K_DIM + kcol);
    uint32_t ow[4];
    #pragma unroll
    for (int q = 0; q < 4; ++q) {
        float4 v = src[q];
        uint32_t b0 = v.x > 0.0f ? 0x01u : 0xFFu;
        uint32_t b1 = v.y > 0.0f ? 0x01u : 0xFFu;
        uint32_t b2 = v.z > 0.0f ? 0x01u : 0xFFu;
        uint32_t b3 = v.w > 0.0f ? 0x01u : 0xFFu;
        ow[q] = b0 | (b1 << 8) | (b2 << 16) | (b3 << 24);
    }
    int4v o; o.x = ow[0]; o.y = ow[1]; o.z = ow[2]; o.w = ow[3];
    *(int4v*)(XBlk + (size_t)u * 1024 + lane * 16) = o;
}

// ====================== W (f32 [in][out]) -> blocked i8 WT ==================
__global__ __launch_bounds__(256) void convert_w_kernel(
        const float* __restrict__ W, int8_t* __restrict__ WBlk) {
    int u    = blockIdx.x * 4 + (threadIdx.x >> 6);   // wave id, [0, 16384)
    int lane = threadIdx.x & 63;
    int p  = u & 3, g = (u >> 2) & 7, kt = (u >> 5) & 31, G = u >> 10;
    int o     = G * 256 + g * 32 + (lane & 31);
    int kbase = kt * 128 + p * 32 + (lane >> 5) * 16;
    const float* src = W + (size_t)kbase * O_DIM + o;
    uint32_t ow[4];
    #pragma unroll
    for (int q = 0; q < 4; ++q) {
        uint32_t v = 0;
        #pragma unroll
        for (int b = 0; b < 4; ++b) {
            float f = src[(size_t)(q * 4 + b) * O_DIM];
            v |= (f > 0.0f ? 0x01u : 0xFFu) << (8 * b);
        }
        ow[q] = v;
    }
    int4v ov; ov.x = ow[0]; ov.y = ow[1]; ov.z = ow[2]; ov.w = ow[3];
    *(int4v*)(WBlk + (size_t)u * 1024 + lane * 16) = ov;
}

// ====================== 256x256 i8 GEMM, reg-dbuf fragments =================
__global__ __launch_bounds__(512, 2) void i8_gemm256_kernel(
        const int8_t* __restrict__ XBlk, const int8_t* __restrict__ WBlk,
        const float* __restrict__ bias, float* __restrict__ out) {
    __shared__ int8_t lds[2 * 65536];    // 128 KiB

    const int tid  = threadIdx.x;
    const int swzb = (blockIdx.x & 7) * 64 + (blockIdx.x >> 3);  // XCD swizzle
    const int brow = (swzb >> 4) * 256;
    const int bcol = (swzb & 15) * 256;

    const int lane = tid & 63;
    const int wid  = tid >> 6;
    const int wrow = (wid >> 2) * 128;   // 2 M-groups
    const int wcol = (wid & 3) * 64;     // 4 N-groups
    const int l31  = lane & 31;
    const int lh   = lane >> 5;

    const int abase = wrow * 128 + lane * 16;
    const int bbase = 32768 + wcol * 128 + lane * 16;

    const size_t ldst0 = (size_t)tid * 16;
    const int8_t* Asrc = XBlk + ((size_t)brow << 12) + ldst0;
    const int8_t* Bsrc = WBlk + ((size_t)bcol << 12) + ldst0;

#define GLOADS(srcbase, ldsoff, kt)                                           \
    {                                                                         \
        _Pragma("unroll")                                                     \
        for (int i = 0; i < 4; ++i) {                                         \
            __builtin_amdgcn_global_load_lds(                                 \
                (const __attribute__((address_space(1))) void*)               \
                    ((srcbase) + (size_t)(kt) * 32768 + i * 8192),            \
                (__attribute__((address_space(3))) void*)                     \
                    (lds + (ldsoff) + ldst0 + i * 8192), 16, 0, 0);           \
        }                                                                     \
    }

    // load fragment set for phase p of buffer at byte offset `off`
#define LOADP(A0, A1, A2, A3, B0, B1, off, p)                                 \
    {                                                                         \
        const int8_t* Ap = lds + (off) + abase + ((p) << 10);                 \
        const int8_t* Bp = lds + (off) + bbase + ((p) << 10);                 \
        A0 = *(const int4v*)(Ap);                                             \
        A1 = *(const int4v*)(Ap + 4096);                                      \
        A2 = *(const int4v*)(Ap + 8192);                                      \
        A3 = *(const int4v*)(Ap + 12288);                                     \
        B0 = *(const int4v*)(Bp);                                             \
        B1 = *(const int4v*)(Bp + 4096);                                      \
    }

#define MFMA8(A0, A1, A2, A3, B0, B1)                                         \
    {                                                                         \
        __builtin_amdgcn_s_setprio(1);                                        \
        c00 = __builtin_amdgcn_mfma_i32_32x32x32_i8(A0, B0, c00, 0, 0, 0);    \
        c01 = __builtin_amdgcn_mfma_i32_32x32x32_i8(A0, B1, c01, 0, 0, 0);    \
        c10 = __builtin_amdgcn_mfma_i32_32x32x32_i8(A1, B0, c10, 0, 0, 0);    \
        c11 = __builtin_amdgcn_mfma_i32_32x32x32_i8(A1, B1, c11, 0, 0, 0);    \
        c20 = __builtin_amdgcn_mfma_i32_32x32x32_i8(A2, B0, c20, 0, 0, 0);    \
        c21 = __builtin_amdgcn_mfma_i32_32x32x32_i8(A2, B1, c21, 0, 0, 0);    \
        c30 = __builtin_amdgcn_mfma_i32_32x32x32_i8(A3, B0, c30, 0, 0, 0);    \
        c31 = __builtin_amdgcn_mfma_i32_32x32x32_i8(A3, B1, c31, 0, 0, 0);    \
        __builtin_amdgcn_s_setprio(0);                                        \
    }

    int16v c00 = 0, c01 = 0, c10 = 0, c11 = 0, c20 = 0, c21 = 0, c30 = 0, c31 = 0;
    int4v a0, a1, a2, a3, b0, b1;        // fragment set A
    int4v na0, na1, na2, na3, nb0, nb1;  // fragment set B

    // prologue: stage tile 0 into buf 0
    GLOADS(Asrc, 0, 0);
    GLOADS(Bsrc, 32768, 0);
    asm volatile("s_waitcnt vmcnt(0)" ::: "memory");
    __builtin_amdgcn_s_barrier();

    for (int t = 0; t < K_DIM / 128; ++t) {
        const int curoff = (t & 1) << 16;
        const int nxtoff = curoff ^ 65536;
        const bool pf = (t < K_DIM / 128 - 1);

        // phase 0 frags (exposed read, post-barrier)
        LOADP(a0, a1, a2, a3, b0, b1, curoff, 0);
        // phase 0: prefetch phase-1 frags + A gloads, then MFMA phase 0
        LOADP(na0, na1, na2, na3, nb0, nb1, curoff, 1);
        if (pf) GLOADS(Asrc, nxtoff, t + 1);
        MFMA8(a0, a1, a2, a3, b0, b1);
        // phase 1: prefetch phase-2 frags + B gloads, then MFMA phase 1
        LOADP(a0, a1, a2, a3, b0, b1, curoff, 2);
        if (pf) GLOADS(Bsrc, nxtoff + 32768, t + 1);
        MFMA8(na0, na1, na2, na3, nb0, nb1);
        // phase 2: prefetch phase-3 frags, then MFMA phase 2
        LOADP(na0, na1, na2, na3, nb0, nb1, curoff, 3);
        MFMA8(a0, a1, a2, a3, b0, b1);
        // phase 3
        MFMA8(na0, na1, na2, na3, nb0, nb1);

        asm volatile("s_waitcnt vmcnt(0)" ::: "memory");  // own staging landed
        __builtin_amdgcn_s_barrier();                     // all reads+stages done
    }
#undef MFMA8
#undef LOADP
#undef GLOADS

    // epilogue: C/D map col=lane&31, row=(r&3)+8*(r>>2)+4*(lane>>5)
    float bv0 = bias[bcol + wcol + l31];
    float bv1 = bias[bcol + wcol + 32 + l31];
    const size_t obase = (size_t)(brow + wrow) * O_DIM + bcol + wcol;

#define CWRITE(cm, m, n, bv)                                                  \
    {                                                                         \
        _Pragma("unroll")                                                     \
        for (int r = 0; r < 16; ++r) {                                        \
            int rl = (r & 3) + 8 * (r >> 2) + 4 * lh;                         \
            out[obase + (size_t)((m) * 32 + rl) * O_DIM + (n) * 32 + l31] =   \
                (float)cm[r] + (bv);                                          \
        }                                                                     \
    }

    CWRITE(c00, 0, 0, bv0); CWRITE(c01, 0, 1, bv1);
    CWRITE(c10, 1, 0, bv0); CWRITE(c11, 1, 1, bv1);
    CWRITE(c20, 2, 0, bv0); CWRITE(c21, 2, 1, bv1);
    CWRITE(c30, 3, 0, bv0); CWRITE(c31, 3, 1, bv1);
#undef CWRITE
}

// ====================== popcount fallback (round-5, proven) =================
__global__ __launch_bounds__(256) void pack_x_kernel(
        const float* __restrict__ X, uint64_t* __restrict__ Xb) {
    int wave = (int)((blockIdx.x * blockDim.x + threadIdx.x) >> 6);
    int lane = threadIdx.x & 63;
    if (wave >= N_ROWS) return;
    const float* xr = X + (size_t)wave * K_DIM;
    uint64_t* xbr = Xb + (size_t)wave * KW;
    #pragma unroll 4
    for (int w = 0; w < KW; ++w) {
        float v = xr[w * 64 + lane];
        unsigned long long m = __ballot(v > 0.0f);
        if (lane == 0) xbr[w] = (uint64_t)m;
    }
}

__global__ __launch_bounds__(256) void pack_w_kernel(
        const float* __restrict__ W, uint64_t* __restrict__ Wb) {
    int oc = blockIdx.x & 15;
    int w  = blockIdx.x >> 4;
    int o  = oc * 256 + threadIdx.x;
    const float* wp = W + (size_t)(w * 64) * O_DIM + o;
    uint64_t word = 0;
    #pragma unroll 8
    for (int p = 0; p < 64; ++p) {
        float v = wp[(size_t)p * O_DIM];
        word |= (uint64_t)(v > 0.0f) << p;
    }
    Wb[(size_t)o * KW + w] = word;
}

__global__ __launch_bounds__(256) void xnor_gemm_kernel(
        const uint8_t* __restrict__ Xb, const uint8_t* __restrict__ Wb,
        const float* __restrict__ bias, float* __restrict__ out) {
    __shared__ uint4 lds4[2048];
    const int tid    = threadIdx.x;
    const int brow   = (blockIdx.x >> 5) * 128;
    const int bcol   = (blockIdx.x & 31) * 128;
    const int tx     = tid & 15;
    const int ty     = tid >> 4;
    const int widx   = tid >> 6;
    const int xbase0 = ty * 64 + (ty & 7);
    const int wbase0 = 1024 + tx * 64 + (tx & 7);
    uint32_t acc[8][8] = {};
    for (int kc = 0; kc < 4; ++kc) {
        __syncthreads();
        #pragma unroll
        for (int i = 0; i < 4; ++i) {
            int idx  = tid + 256 * i;
            int row  = idx >> 3;
            int srcc = (idx & 7) ^ ((idx >> 6) & 7);
            size_t goff = ((size_t)row << 9) + (kc << 7) + (srcc << 4);
            __builtin_amdgcn_global_load_lds(
                (const __attribute__((address_space(1))) void*)
                    (Xb + ((size_t)brow << 9) + goff),
                (__attribute__((address_space(3))) void*)
                    (lds4 + i * 256 + widx * 64), 16, 0, 0);
            __builtin_amdgcn_global_load_lds(
                (const __attribute__((address_space(1))) void*)
                    (Wb + ((size_t)bcol << 9) + goff),
                (__attribute__((address_space(3))) void*)
                    (lds4 + 1024 + i * 256 + widx * 64), 16, 0, 0);
        }
        asm volatile("s_waitcnt vmcnt(0)" ::: "memory");
        __syncthreads();
        for (int kq = 0; kq < 8; ++kq) {
            const uint4* xp = &lds4[xbase0 ^ kq];
            const uint4* wp = &lds4[wbase0 ^ kq];
            uint4 xq[8];
            #pragma unroll
            for (int r = 0; r < 8; ++r) xq[r] = xp[8 * r];
            #pragma unroll
            for (int c = 0; c < 8; ++c) {
                uint4 wv = wp[8 * c];
                #pragma unroll
                for (int r = 0; r < 8; ++r) {
                    uint32_t a = acc[r][c];
                    a = __builtin_popcount(xq[r].x ^ wv.x) + a;
                    a = __builtin_popcount(xq[r].y ^ wv.y) + a;
                    a = __builtin_popcount(xq[r].z ^ wv.z) + a;
                    a = __builtin_popcount(xq[r].w ^ wv.w) + a;
                    acc[r][c] = a;
                }
            }
        }
    }
    float bv[8];
    #pragma unroll
    for (int c = 0; c < 8; ++c) bv[c] = bias[bcol + tx * 8 + c];
    #pragma unroll
    for (int r = 0; r < 8; ++r) {
        float vals[8];
        #pragma unroll
        for (int c = 0; c < 8; ++c)
            vals[c] = (float)(K_DIM - 2 * (int)acc[r][c]) + bv[c];
        float4* op = (float4*)(out + (size_t)(brow + ty * 8 + r) * O_DIM
                               + bcol + tx * 8);
        op[0] = make_float4(vals[0], vals[1], vals[2], vals[3]);
        op[1] = make_float4(vals[4], vals[5], vals[6], vals[7]);
    }
}

// ====================== launcher ============================================
extern "C" void kernel_launch(void* const* d_in, const int* in_sizes, int n_in,
                              void* d_out, int out_size, void* d_ws, size_t ws_size,
                              hipStream_t stream) {
    const float* X    = (const float*)d_in[0];
    const float* W    = (const float*)d_in[1];
    const float* bias = (const float*)d_in[2];
    float* out        = (float*)d_out;

    const size_t XB_BYTES = (size_t)N_ROWS * K_DIM;   // 32 MiB blocked X
    const size_t WB_BYTES = (size_t)O_DIM * K_DIM;    // 16 MiB blocked W

    if (ws_size >= XB_BYTES + WB_BYTES) {
        int8_t* XBlk = (int8_t*)d_ws;
        int8_t* WBlk = (int8_t*)d_ws + XB_BYTES;

        convert_x_kernel<<<(N_ROWS * K_DIM / 16) / 256, 256, 0, stream>>>(X, XBlk);
        convert_w_kernel<<<(O_DIM * K_DIM / 16) / 256, 256, 0, stream>>>(W, WBlk);
        i8_gemm256_kernel<<<(N_ROWS / 256) * (O_DIM / 256), 512, 0, stream>>>(
            XBlk, WBlk, bias, out);
    } else {
        uint64_t* Xb = (uint64_t*)d_ws;
        uint64_t* Wb = (uint64_t*)((uint8_t*)d_ws + (size_t)N_ROWS * KW * 8);
        pack_x_kernel<<<N_ROWS / 4, 256, 0, stream>>>(X, Xb);
        pack_w_kernel<<<16 * 64, 256, 0, stream>>>(W, Wb);
        xnor_gemm_kernel<<<(N_ROWS / 128) * (O_DIM / 128), 256, 0, stream>>>(
            (const uint8_t*)Xb, (const uint8_t*)Wb, bias, out);
    }
}